// Round 7
// baseline (125.614 us; speedup 1.0000x reference)
//
#include <hip/hip_runtime.h>
#include <hip/hip_bf16.h>

typedef short v8s __attribute__((ext_vector_type(8)));
typedef float v16f __attribute__((ext_vector_type(16)));
typedef unsigned v2u __attribute__((ext_vector_type(2)));

#define F_ 128
#define K_ 512
#define M_ 65536
#define NCH 16        // 16 chunks of 32 clusters
#define CH_SH 8704    // shorts per chunk table: Cb' 4608 (9 ks x 2h x 32c x 8) + CT' 4096
#define CT_OFF 4608

typedef __attribute__((address_space(1))) const char gch;
typedef __attribute__((address_space(3))) char lch;

__device__ __forceinline__ short f2bf(float f) {
    union { float f; unsigned u; } v; v.f = f;
    unsigned u = v.u;
    u = (u + 0x7FFFu + ((u >> 16) & 1u)) >> 16;  // RNE
    return (short)u;
}
__device__ __forceinline__ float bf2f(short s) {
    union { float f; unsigned u; } v;
    v.u = ((unsigned)(unsigned short)s) << 16;
    return v.f;
}

#if __has_builtin(__builtin_amdgcn_permlane32_swap)
#define HAVE_PLS 1
#endif

// (a,b) -> (a.lo||b.lo, a.hi||b.hi): half-wave exchange for C->A layout (verified R4).
__device__ __forceinline__ void pswap(unsigned &a, unsigned &b, int lane) {
#ifdef HAVE_PLS
    v2u r = __builtin_amdgcn_permlane32_swap(a, b, false, false);
    a = (unsigned)r.x; b = (unsigned)r.y;
#else
    unsigned sa = (unsigned)__shfl_xor((int)a, 32);
    unsigned sb = (unsigned)__shfl_xor((int)b, 32);
    if (lane & 32) a = sb; else b = sa;
#endif
}

// Per-chunk tables (32 clusters) in fragment-granule order.
// Cb' granule (ks,h,c32): stage-1 A-frag bytes; ks=8 rows hold the norm augmentation.
// CT' granule (kap,h,f): stage-2 B-frag bytes.
__global__ void prep_kernel(const float* __restrict__ centers, short* __restrict__ G) {
    const int c = blockIdx.x;     // 512 clusters
    const int f = threadIdx.x;    // 128 features
    const int ch = c >> 5, c32 = c & 31;
    const size_t base = (size_t)ch * CH_SH;
    float v = centers[c * F_ + f];
    short b = f2bf(v);
    float vb = bf2f(b);
    { const int ks = f >> 4, h = (f >> 3) & 1, j = f & 7;
      G[base + (size_t)((ks * 2 + h) * 32 + c32) * 8 + j] = b; }
    { const int kap = c32 >> 4, hh = (c32 >> 3) & 1, jj = c32 & 7;
      G[base + CT_OFF + (size_t)((kap * 2 + hh) * F_ + f) * 8 + jj] = b; }
    float s = vb * vb;
    #pragma unroll
    for (int off = 1; off < 64; off <<= 1) s += __shfl_xor(s, off);
    __shared__ float part[2];
    if ((f & 63) == 0) part[f >> 6] = s;
    __syncthreads();
    if (f < 16) {
        const float csq = part[0] + part[1];
        const float chv = -0.5f * csq;
        const short vh = f2bf(chv);
        const short vl = f2bf(chv - bf2f(vh));
        const short val = (f == 0) ? vh : (f == 1) ? vl : (f == 2) ? (short)0x3F80 : (short)0;
        const int h2 = f >> 3, j2 = f & 7;
        G[base + (size_t)((16 + h2) * 32 + c32) * 8 + j2] = val;
    }
}

// Linear 17 KB chunk copy (1088 granules) via async DMA.
__device__ __forceinline__ void stage_chunk(const short* __restrict__ G, short* dst,
                                            int ch, int wave, int lane) {
    const char* src = (const char*)(G + (size_t)ch * CH_SH);
    lch* d = (lch*)dst;
    #pragma unroll
    for (int t = 0; t < 4; ++t) {
        const int g = t * 256 + wave * 64 + lane;
        __builtin_amdgcn_global_load_lds((gch*)(src + (size_t)g * 16),
                                         d + (size_t)(t * 256 + wave * 64) * 16, 16, 0, 0);
    }
    if (wave == 0)
        __builtin_amdgcn_global_load_lds((gch*)(src + (size_t)(1024 + lane) * 16),
                                         d + (size_t)1024 * 16, 16, 0, 0);
}

// FA-style lagged pipeline: iteration j does stage-1(j) MFMA chain, stage-2(j-1)
// (P carried in registers across the barrier), epilogue(j) transcendentals — all
// independent chains in one scheduling region. Staging of chunk j+2 issues right
// after barrier-j and is consumed a full iteration later (drain ~free).
__global__ __launch_bounds__(256, 2) void cluster_kernel(
        const float* __restrict__ x, const short* __restrict__ G,
        float* __restrict__ out) {
    __shared__ __align__(16) short SB[3][CH_SH];   // 3 x 17 KB rotating buffers
    const int tid = threadIdx.x;
    const int wave = tid >> 6, lane = tid & 63;
    const int h = lane >> 5, c32 = lane & 31;
    const int row0 = blockIdx.x * 128 + wave * 32;

    // ---- x prologue: issue all 16 loads, then convert ----
    const float4* xr4 = (const float4*)(x + (size_t)(row0 + c32) * F_);
    float4 xl[16];
    #pragma unroll
    for (int ks = 0; ks < 8; ++ks) {
        xl[2 * ks]     = xr4[ks * 4 + h * 2];
        xl[2 * ks + 1] = xr4[ks * 4 + h * 2 + 1];
    }
    v8s Bx[9];
    float xs = 0.f;
    #pragma unroll
    for (int ks = 0; ks < 8; ++ks) {
        float vv[8] = {xl[2*ks].x, xl[2*ks].y, xl[2*ks].z, xl[2*ks].w,
                       xl[2*ks+1].x, xl[2*ks+1].y, xl[2*ks+1].z, xl[2*ks+1].w};
        v8s fr;
        #pragma unroll
        for (int j = 0; j < 8; ++j) {
            short bb = f2bf(vv[j]);
            fr[j] = bb;
            float r = bf2f(bb);
            xs += r * r;        // ||x~||^2 of bf16-rounded values
        }
        Bx[ks] = fr;
    }
    xs += __shfl_xor(xs, 32);
    {
        const float xh = -0.5f * xs;
        const short sxh = f2bf(xh);
        const short sxl = f2bf(xh - bf2f(sxh));
        v8s e = (v8s){0, 0, 0, 0, 0, 0, 0, 0};
        if (h == 0) { e[0] = (short)0x3F80; e[1] = (short)0x3F80; e[2] = sxh; e[3] = sxl; }
        Bx[8] = e;              // k=128..131 norm augmentation (verified R4)
    }

    v16f Of[4];
    #pragma unroll
    for (int ft = 0; ft < 4; ++ft)
        #pragma unroll
        for (int e2 = 0; e2 < 16; ++e2) Of[ft][e2] = 0.f;
    float lden = 0.f;

    const int off = blockIdx.x & 15;
    stage_chunk(G, SB[0], off, wave, lane);
    stage_chunk(G, SB[1], (off + 1) & 15, wave, lane);
    __syncthreads();            // implicit vmcnt drain covers both staged chunks

    v8s pf0c = (v8s){0,0,0,0,0,0,0,0}, pf1c = (v8s){0,0,0,0,0,0,0,0};

    #pragma unroll
    for (int j = 0; j < NCH; ++j) {
        const short* CbS = SB[j % 3];

        // ---- stage-1(j): 9-step MFMA chain (A from LDS, B=x in regs) ----
        v16f acc;
        #pragma unroll
        for (int e2 = 0; e2 < 16; ++e2) acc[e2] = 0.f;
        #pragma unroll
        for (int ks = 0; ks < 9; ++ks) {
            v8s af = *(const v8s*)&CbS[(size_t)((ks * 2 + h) * 32 + c32) * 8];
            acc = __builtin_amdgcn_mfma_f32_32x32x16_bf16(af, Bx[ks], acc, 0, 0, 0);
        }

        // ---- stage-2(j-1): independent Of chains fill stage-1's latency ----
        if (j > 0) {
            const short* CTp = SB[(j - 1) % 3] + CT_OFF;
            v8s cfv[8];
            #pragma unroll
            for (int kp = 0; kp < 2; ++kp)
                #pragma unroll
                for (int ft = 0; ft < 4; ++ft)
                    cfv[kp * 4 + ft] = *(const v8s*)
                        &CTp[(size_t)((kp * 2 + h) * F_ + ft * 32 + c32) * 8];
            #pragma unroll
            for (int ft = 0; ft < 4; ++ft) {
                Of[ft] = __builtin_amdgcn_mfma_f32_32x32x16_bf16(pf0c, cfv[ft], Of[ft], 0, 0, 0);
                Of[ft] = __builtin_amdgcn_mfma_f32_32x32x16_bf16(pf1c, cfv[4 + ft], Of[ft], 0, 0, 0);
            }
        }

        // ---- epilogue(j): (d*log2e)^2 = 4.16274*(-acc); p = exp2(-sqrt(.)) ----
        unsigned U[8];
        #pragma unroll
        for (int t = 0; t < 8; ++t) {
            const float s20 = fmaxf(-4.16273796f * acc[2 * t], 0.f);
            const float s21 = fmaxf(-4.16273796f * acc[2 * t + 1], 0.f);
            const float p0 = __builtin_amdgcn_exp2f(-__builtin_amdgcn_sqrtf(s20));
            const float p1 = __builtin_amdgcn_exp2f(-__builtin_amdgcn_sqrtf(s21));
            lden += p0 + p1;     // f32 denom (pre-rounding): shifts output ~1e-4, OK
            union { __hip_bfloat162 hh; unsigned u; } cv;
            cv.hh = __float22bfloat162_rn(make_float2(p0, p1));
            U[t] = cv.u;
        }
        // C-layout -> A-layout (verified R4): 2 swaps per kp, all in registers.
        #pragma unroll
        for (int kp = 0; kp < 2; ++kp) {
            unsigned s0 = U[4 * kp],     s2 = U[4 * kp + 2];
            unsigned s1 = U[4 * kp + 1], s3 = U[4 * kp + 3];
            pswap(s0, s2, lane);
            pswap(s1, s3, lane);
            union { v8s v; unsigned u[4]; } pf;
            pf.u[0] = s0; pf.u[1] = s1; pf.u[2] = s2; pf.u[3] = s3;
            if (kp == 0) pf0c = pf.v; else pf1c = pf.v;
        }

        if (j < NCH - 1) __syncthreads();   // drains only iteration-old staging loads
        if (j < NCH - 2)
            stage_chunk(G, SB[(j + 2) % 3], (off + j + 2) & 15, wave, lane);
    }

    // ---- tail: stage-2 for the last chunk ----
    {
        const short* CTp = SB[(NCH - 1) % 3] + CT_OFF;
        #pragma unroll
        for (int kp = 0; kp < 2; ++kp) {
            const v8s pf = kp ? pf1c : pf0c;
            #pragma unroll
            for (int ft = 0; ft < 4; ++ft) {
                v8s cf = *(const v8s*)&CTp[(size_t)((kp * 2 + h) * F_ + ft * 32 + c32) * 8];
                Of[ft] = __builtin_amdgcn_mfma_f32_32x32x16_bf16(pf, cf, Of[ft], 0, 0, 0);
            }
        }
    }

    // Denominator: lane sum covers all 512 clusters of row c32 after h-halves merge.
    lden += __shfl_xor(lden, 32);
    const float inv = 1.0f / lden;
    float invr[16];
    #pragma unroll
    for (int r = 0; r < 16; ++r)
        invr[r] = __shfl(inv, (r & 3) + 8 * (r >> 2) + 4 * h);
    #pragma unroll
    for (int ft = 0; ft < 4; ++ft)
        #pragma unroll
        for (int r = 0; r < 16; ++r) {
            const int xrow = (r & 3) + 8 * (r >> 2) + 4 * h;
            out[(size_t)(row0 + xrow) * F_ + ft * 32 + c32] = Of[ft][r] * invr[r];
        }
}

extern "C" void kernel_launch(void* const* d_in, const int* in_sizes, int n_in,
                              void* d_out, int out_size, void* d_ws, size_t ws_size,
                              hipStream_t stream) {
    const float* x       = (const float*)d_in[0];   // [8,8192,128] fp32
    const float* centers = (const float*)d_in[1];   // [512,128] fp32
    float* out = (float*)d_out;                     // [8,8192,128] fp32
    short* G = (short*)d_ws;                        // 16 chunks x 17408 B = 278528 B
    prep_kernel<<<K_, F_, 0, stream>>>(centers, G);
    cluster_kernel<<<M_ / 128, 256, 0, stream>>>(x, G, out);
}

// Round 8
// 103.193 us; speedup vs baseline: 1.2173x; 1.2173x over previous
//
#include <hip/hip_runtime.h>
#include <hip/hip_bf16.h>

typedef short v8s __attribute__((ext_vector_type(8)));
typedef float v16f __attribute__((ext_vector_type(16)));
typedef unsigned v2u __attribute__((ext_vector_type(2)));

#define F_ 128
#define K_ 512
#define M_ 65536
#define CH_SH 17408   // shorts per chunk table: Cb' 9216 (64c x 144f) + CT' 8192 (64c x 128f)
#define CB_OFF 9216

typedef __attribute__((address_space(1))) const char gch;
typedef __attribute__((address_space(3))) char lch;

__device__ __forceinline__ short f2bf(float f) {
    union { float f; unsigned u; } v; v.f = f;
    unsigned u = v.u;
    u = (u + 0x7FFFu + ((u >> 16) & 1u)) >> 16;  // RNE
    return (short)u;
}
__device__ __forceinline__ float bf2f(short s) {
    union { float f; unsigned u; } v;
    v.u = ((unsigned)(unsigned short)s) << 16;
    return v.f;
}

#if __has_builtin(__builtin_amdgcn_permlane32_swap)
#define HAVE_PLS 1
#endif

// (a,b) -> (a.lo||b.lo, a.hi||b.hi): half-wave exchange for C->A layout (verified R4).
__device__ __forceinline__ void pswap(unsigned &a, unsigned &b, int lane) {
#ifdef HAVE_PLS
    v2u r = __builtin_amdgcn_permlane32_swap(a, b, false, false);
    a = (unsigned)r.x; b = (unsigned)r.y;
#else
    unsigned sa = (unsigned)__shfl_xor((int)a, 32);
    unsigned sb = (unsigned)__shfl_xor((int)b, 32);
    if (lane & 32) a = sb; else b = sa;
#endif
}

// Build combined per-chunk tables in fragment-granule order (verified R4/R6).
__global__ void prep_kernel(const float* __restrict__ centers, short* __restrict__ G) {
    const int c = blockIdx.x;     // 512 clusters
    const int f = threadIdx.x;    // 128 features
    const int ch = c >> 6, c64 = c & 63;
    const size_t base = (size_t)ch * CH_SH;
    float v = centers[c * F_ + f];
    short b = f2bf(v);
    float vb = bf2f(b);
    { const int ks = f >> 4, h = (f >> 3) & 1, j = f & 7;
      G[base + (size_t)((ks * 2 + h) * 64 + c64) * 8 + j] = b; }
    { const int kap = c64 >> 4, hh = (c64 >> 3) & 1, jj = c64 & 7;
      G[base + CB_OFF + (size_t)((kap * 2 + hh) * F_ + f) * 8 + jj] = b; }
    float s = vb * vb;
    #pragma unroll
    for (int off = 1; off < 64; off <<= 1) s += __shfl_xor(s, off);
    __shared__ float part[2];
    if ((f & 63) == 0) part[f >> 6] = s;
    __syncthreads();
    if (f < 16) {
        const float csq = part[0] + part[1];
        const float chv = -0.5f * csq;
        const short vh = f2bf(chv);
        const short vl = f2bf(chv - bf2f(vh));
        const short val = (f == 0) ? vh : (f == 1) ? vl : (f == 2) ? (short)0x3F80 : (short)0;
        const int h2 = f >> 3, j2 = f & 7;
        G[base + (size_t)((16 + h2) * 64 + c64) * 8 + j2] = val;
    }
}

// Linear 34 KB chunk copy (2176 granules) via async DMA, 512 threads.
__device__ __forceinline__ void stage_chunk(const short* __restrict__ G, short* dst,
                                            int ch, int wave, int lane) {
    const char* src = (const char*)(G + (size_t)ch * CH_SH);
    lch* d = (lch*)dst;
    #pragma unroll
    for (int t = 0; t < 4; ++t) {
        const int g = t * 512 + wave * 64 + lane;
        __builtin_amdgcn_global_load_lds((gch*)(src + (size_t)g * 16),
                                         d + (size_t)(t * 512 + wave * 64) * 16, 16, 0, 0);
    }
    if (wave < 2) {
        const int g = 2048 + wave * 64 + lane;
        __builtin_amdgcn_global_load_lds((gch*)(src + (size_t)g * 16),
                                         d + (size_t)(2048 + wave * 64) * 16, 16, 0, 0);
    }
}

// 512-thread blocks (8 waves x 32 rows), grid 256 = 1 block/CU: table staged ONCE
// per CU per pass (halved DMA). Triple-buffered 64c chunks; barrier at loop top
// drains staging issued one full iteration earlier (~free drain).
__global__ __launch_bounds__(512, 2) void cluster_kernel(
        const float* __restrict__ x, const short* __restrict__ G,
        float* __restrict__ out) {
    __shared__ __align__(16) short SB[3][CH_SH];   // 3 x 34 KB rotating buffers
    const int tid = threadIdx.x;
    const int wave = tid >> 6, lane = tid & 63;
    const int h = lane >> 5, c32 = lane & 31;
    const int row0 = blockIdx.x * 256 + wave * 32;

    // ---- x prologue: issue all 16 loads, then convert ----
    const float4* xr4 = (const float4*)(x + (size_t)(row0 + c32) * F_);
    float4 xl[16];
    #pragma unroll
    for (int ks = 0; ks < 8; ++ks) {
        xl[2 * ks]     = xr4[ks * 4 + h * 2];
        xl[2 * ks + 1] = xr4[ks * 4 + h * 2 + 1];
    }
    v8s Bx[9];
    float xs = 0.f;
    #pragma unroll
    for (int ks = 0; ks < 8; ++ks) {
        float vv[8] = {xl[2*ks].x, xl[2*ks].y, xl[2*ks].z, xl[2*ks].w,
                       xl[2*ks+1].x, xl[2*ks+1].y, xl[2*ks+1].z, xl[2*ks+1].w};
        v8s fr;
        #pragma unroll
        for (int j = 0; j < 8; ++j) {
            short bb = f2bf(vv[j]);
            fr[j] = bb;
            float r = bf2f(bb);
            xs += r * r;        // ||x~||^2 of bf16-rounded values
        }
        Bx[ks] = fr;
    }
    xs += __shfl_xor(xs, 32);
    {
        const float xh = -0.5f * xs;
        const short sxh = f2bf(xh);
        const short sxl = f2bf(xh - bf2f(sxh));
        v8s e = (v8s){0, 0, 0, 0, 0, 0, 0, 0};
        if (h == 0) { e[0] = (short)0x3F80; e[1] = (short)0x3F80; e[2] = sxh; e[3] = sxl; }
        Bx[8] = e;              // k=128..131 norm augmentation (verified R4)
    }

    v16f Of[4];
    #pragma unroll
    for (int ft = 0; ft < 4; ++ft)
        #pragma unroll
        for (int e2 = 0; e2 < 16; ++e2) Of[ft][e2] = 0.f;
    float lden = 0.f;

    short* const SB0 = &SB[0][0];
    const int off = blockIdx.x & 7;
    stage_chunk(G, SB0, off, wave, lane);
    stage_chunk(G, SB0 + CH_SH, (off + 1) & 7, wave, lane);

    #pragma unroll 1
    for (int j = 0; j < 8; ++j) {
        __syncthreads();        // implicit vmcnt drain: staging is one iteration old
        if (j < 6)
            stage_chunk(G, SB0 + (size_t)((j + 2) % 3) * CH_SH, (off + j + 2) & 7, wave, lane);
        const short* CbS = SB0 + (size_t)(j % 3) * CH_SH;
        const short* CTS = CbS + CB_OFF;

        // ---- stage 1: two independent chains, sliding 2-deep A-frag window ----
        v16f a0, a1;
        #pragma unroll
        for (int e2 = 0; e2 < 16; ++e2) { a0[e2] = 0.f; a1[e2] = 0.f; }
        {
            v8s f0a = *(const v8s*)&CbS[(size_t)((0 * 2 + h) * 64 + c32) * 8];
            v8s f1a = *(const v8s*)&CbS[(size_t)((0 * 2 + h) * 64 + 32 + c32) * 8];
            v8s f0b = *(const v8s*)&CbS[(size_t)((1 * 2 + h) * 64 + c32) * 8];
            v8s f1b = *(const v8s*)&CbS[(size_t)((1 * 2 + h) * 64 + 32 + c32) * 8];
            #pragma unroll
            for (int ks = 0; ks < 9; ++ks) {
                v8s c0 = f0a, c1 = f1a;
                f0a = f0b; f1a = f1b;
                if (ks < 7) {
                    f0b = *(const v8s*)&CbS[(size_t)(((ks + 2) * 2 + h) * 64 + c32) * 8];
                    f1b = *(const v8s*)&CbS[(size_t)(((ks + 2) * 2 + h) * 64 + 32 + c32) * 8];
                }
                a0 = __builtin_amdgcn_mfma_f32_32x32x16_bf16(c0, Bx[ks], a0, 0, 0, 0);
                a1 = __builtin_amdgcn_mfma_f32_32x32x16_bf16(c1, Bx[ks], a1, 0, 0, 0);
            }
        }

        // ---- per ct tile: cf prefetch (hidden under exp chain) + epilogue + stage-2 ----
        #pragma unroll
        for (int ct = 0; ct < 2; ++ct) {
            v8s cf[8];
            #pragma unroll
            for (int kp = 0; kp < 2; ++kp)
                #pragma unroll
                for (int ft = 0; ft < 4; ++ft)
                    cf[kp * 4 + ft] = *(const v8s*)
                        &CTS[(size_t)(((ct * 2 + kp) * 2 + h) * F_ + ft * 32 + c32) * 8];
            const v16f acc = ct ? a1 : a0;
            unsigned U[8];
            #pragma unroll
            for (int t = 0; t < 8; ++t) {
                const float d20 = fmaxf(-2.0f * acc[2 * t], 0.f);
                const float d21 = fmaxf(-2.0f * acc[2 * t + 1], 0.f);
                const float p0 = __expf(-__builtin_amdgcn_sqrtf(d20));
                const float p1 = __expf(-__builtin_amdgcn_sqrtf(d21));
                union { __hip_bfloat162 hh; unsigned u; } cv;
                cv.hh = __float22bfloat162_rn(make_float2(p0, p1));
                U[t] = cv.u;
                lden += __uint_as_float(cv.u << 16);        // denom from SAME rounded p
                lden += __uint_as_float(cv.u & 0xffff0000u);
            }
            #pragma unroll
            for (int kp = 0; kp < 2; ++kp) {
                unsigned s0 = U[4 * kp],     s2 = U[4 * kp + 2];
                unsigned s1 = U[4 * kp + 1], s3 = U[4 * kp + 3];
                pswap(s0, s2, lane);
                pswap(s1, s3, lane);
                union { v8s v; unsigned u[4]; } pf;
                pf.u[0] = s0; pf.u[1] = s1; pf.u[2] = s2; pf.u[3] = s3;
                #pragma unroll
                for (int ft = 0; ft < 4; ++ft)
                    Of[ft] = __builtin_amdgcn_mfma_f32_32x32x16_bf16(pf.v, cf[kp * 4 + ft], Of[ft], 0, 0, 0);
            }
        }
    }

    // Denominator: lane sum covers all 512 clusters of row c32 after h-halves merge.
    lden += __shfl_xor(lden, 32);
    const float inv = 1.0f / lden;
    float invr[16];
    #pragma unroll
    for (int r = 0; r < 16; ++r)
        invr[r] = __shfl(inv, (r & 3) + 8 * (r >> 2) + 4 * h);
    #pragma unroll
    for (int ft = 0; ft < 4; ++ft)
        #pragma unroll
        for (int r = 0; r < 16; ++r) {
            const int xrow = (r & 3) + 8 * (r >> 2) + 4 * h;
            out[(size_t)(row0 + xrow) * F_ + ft * 32 + c32] = Of[ft][r] * invr[r];
        }
}

extern "C" void kernel_launch(void* const* d_in, const int* in_sizes, int n_in,
                              void* d_out, int out_size, void* d_ws, size_t ws_size,
                              hipStream_t stream) {
    const float* x       = (const float*)d_in[0];   // [8,8192,128] fp32
    const float* centers = (const float*)d_in[1];   // [512,128] fp32
    float* out = (float*)d_out;                     // [8,8192,128] fp32
    short* G = (short*)d_ws;                        // 8 chunks x 34816 B = 278528 B
    prep_kernel<<<K_, F_, 0, stream>>>(centers, G);
    cluster_kernel<<<M_ / 256, 512, 0, stream>>>(x, G, out);
}